// Round 7
// baseline (269.820 us; speedup 1.0000x reference)
//
#include <hip/hip_runtime.h>
#include <stdint.h>
#include <math.h>

typedef float  f32x4  __attribute__((ext_vector_type(4)));
typedef __bf16 bf16x8 __attribute__((ext_vector_type(8)));
typedef __bf16 bf16x4 __attribute__((ext_vector_type(4)));

#define MFMA16(a, b, c) __builtin_amdgcn_mfma_f32_16x16x32_bf16((a), (b), (c), 0, 0, 0)

static constexpr int kT    = 1024;
static constexpr int kLS   = 72;            // padded row stride in bf16 (144 B, 16B-aligned)
static constexpr int kTile = 64 * kLS;      // 4608 el = 9216 B per 64x64 tile
static constexpr size_t kTensorEl    = (size_t)128 * 16 * kTile;   // 9,437,184 el
static constexpr size_t kTensorBytes = kTensorEl * 2;              // 18,874,368 B

// ---------------- Prepass: fp32 -> bf16 (Q/K hi+lo split, V hi only) ----------------
// Folds: Q *= 0.125*log2(e)  (so MFMA output is the exp2 argument),
//        K *= mask[s]        (mask depends only on s: S*m == (m*K)^T Q).
// Layout per tensor: [bh 128][tile 16][row 64][kLS 72] bf16.
// Q^T/K^T rows = t|s, cols = c (transposed via LDS). V rows = c, cols = s (direct).
// Crucial property: every MFMA fragment (8 bf16 at row*72 + kc*32 + quad*8) is a
// contiguous 16B-aligned chunk in global memory -> main kernel loads frags directly.
__global__ __launch_bounds__(256, 4)
void prepass(const float* __restrict__ qkv, const float* __restrict__ mask,
             __bf16* __restrict__ qh, __bf16* __restrict__ qlo,
             __bf16* __restrict__ kh, __bf16* __restrict__ klo,
             __bf16* __restrict__ vh)
{
  __shared__ float tq[64 * 65];   // fp32 staging for transpose (stride 65: conflict-free)
  __shared__ float tk[64 * 65];
  const int tid = threadIdx.x;
  const int bid = blockIdx.x, bh = bid >> 4, tile = bid & 15;
  const int b = bh >> 4, h = bh & 15, t0 = tile * 64;
  const float* __restrict__ qb = qkv + (size_t)(b * 3072 + h * 64) * kT;
  const float* __restrict__ kb = qkv + (size_t)(b * 3072 + 1024 + h * 64) * kT;
  const float* __restrict__ vb = qkv + (size_t)(b * 3072 + 2048 + h * 64) * kT;
  const float* __restrict__ mrow = mask + (size_t)(h & 7) * kT;  // mask.repeat(n_heads,1)
  const size_t tbase = ((size_t)bh * 16 + tile) * kTile;

  // load phase: float4 per thread; V converts+stores directly (t contiguous)
  const int t4   = (tid & 15) * 4;
  const int crow = tid >> 4;
  const f32x4 m4 = *(const f32x4*)&mrow[t0 + t4];   // same t-slice for all c rows
  #pragma unroll
  for (int i = 0; i < 4; ++i) {
    const int c = i * 16 + crow;
    f32x4 q4 = *(const f32x4*)&qb[(size_t)c * kT + t0 + t4];
    q4 *= 0.18033688f;                 // 0.125 * log2(e)
    *(f32x4*)&tq[c * 65 + t4] = q4;
    f32x4 k4 = *(const f32x4*)&kb[(size_t)c * kT + t0 + t4];
    k4 *= m4;                          // fold mask into K rows (s-axis)
    *(f32x4*)&tk[c * 65 + t4] = k4;
    f32x4 v4 = *(const f32x4*)&vb[(size_t)c * kT + t0 + t4];
    bf16x4 v4h;
    #pragma unroll
    for (int j = 0; j < 4; ++j) v4h[j] = (__bf16)v4[j];
    *(bf16x4*)&vh[tbase + c * kLS + t4] = v4h;
  }
  __syncthreads();

  // transpose phase: b64 stores, 4 consecutive c per lane
  const int c0 = tid & 15;
  const int rr = tid >> 4;
  #pragma unroll
  for (int i = 0; i < 4; ++i) {
    const int row = i * 16 + rr;
    bf16x4 qh4, ql4, kh4, kl4;
    #pragma unroll
    for (int j = 0; j < 4; ++j) {
      float q = tq[(c0 * 4 + j) * 65 + row];
      __bf16 qhi = (__bf16)q;
      qh4[j] = qhi; ql4[j] = (__bf16)(q - (float)qhi);
      float k = tk[(c0 * 4 + j) * 65 + row];
      __bf16 khi = (__bf16)k;
      kh4[j] = khi; kl4[j] = (__bf16)(k - (float)khi);
    }
    const size_t o = tbase + row * kLS + c0 * 4;
    *(bf16x4*)&qh [o] = qh4;
    *(bf16x4*)&qlo[o] = ql4;
    *(bf16x4*)&kh [o] = kh4;
    *(bf16x4*)&klo[o] = kl4;
  }
}

// ---------------- Main: barrier-free flash attention ----------------
// K/V MFMA fragments are loaded DIRECTLY global->VGPR (prepass layout makes every
// fragment a contiguous 16B chunk). No LDS staging, no __syncthreads anywhere:
// the compiler pipelines loads against MFMA with fine-grained vmcnt (AITER-style).
// LDS holds only the wave-private P relayout (in-wave DS ordering suffices).
// Denominator via ones-MFMA C-frag. 128 t-columns per block (2 halves per wave).
__global__ __launch_bounds__(256, 3)
void attn_main(const __bf16* __restrict__ qh, const __bf16* __restrict__ qlo,
               const __bf16* __restrict__ kh, const __bf16* __restrict__ klo,
               const __bf16* __restrict__ vh, float* __restrict__ out)
{
  __shared__ __align__(16) __bf16 sP[128 * kLS];  // rows: wave*32 + half*16 + l15

  const int tid  = threadIdx.x;
  const int lane = tid & 63;
  const int wave = tid >> 6;
  const int quad = lane >> 4;
  const int l15  = lane & 15;

  const int bid = blockIdx.x;
  const int bh  = bid & 127;       // head-major: blocks of one head share XCD
  const int tp  = bid >> 7;        // t-pair 0..7
  const int b   = bh >> 4;
  const int h   = bh & 15;
  const int t0  = tp * 128;

  const size_t hbase = (size_t)bh * 16;

  bf16x8 ones8;
  #pragma unroll
  for (int j = 0; j < 8; ++j) ones8[j] = (__bf16)1.0f;

  // per-lane fragment offsets within a 64x72 tile: row i*16+l15, chunk quad*8
  int ro[4];
  #pragma unroll
  for (int i = 0; i < 4; ++i) ro[i] = (i * 16 + l15) * kLS + quad * 8;

  // ---- Q frags: direct global loads (row = wave*16+l15 of tiles tp*2, tp*2+1) ----
  bf16x8 qhf[2][2], qlf[2][2];
  {
    const size_t qt0 = (hbase + tp * 2 + 0) * kTile + (size_t)(wave * 16 + l15) * kLS + quad * 8;
    const size_t qt1 = (hbase + tp * 2 + 1) * kTile + (size_t)(wave * 16 + l15) * kLS + quad * 8;
    #pragma unroll
    for (int kc = 0; kc < 2; ++kc) {
      qhf[0][kc] = *(const bf16x8*)&qh [qt0 + kc * 32];
      qlf[0][kc] = *(const bf16x8*)&qlo[qt0 + kc * 32];
      qhf[1][kc] = *(const bf16x8*)&qh [qt1 + kc * 32];
      qlf[1][kc] = *(const bf16x8*)&qlo[qt1 + kc * 32];
    }
  }

  f32x4 O0[4], O1[4];
  #pragma unroll
  for (int cc = 0; cc < 4; ++cc) {
    O0[cc] = (f32x4){0.f, 0.f, 0.f, 0.f};
    O1[cc] = (f32x4){0.f, 0.f, 0.f, 0.f};
  }
  f32x4 L0 = (f32x4){0.f, 0.f, 0.f, 0.f};
  f32x4 L1 = (f32x4){0.f, 0.f, 0.f, 0.f};

  const int pw0 = (wave * 32 + l15) * kLS;        // sP row base, half A
  const int pw1 = (wave * 32 + 16 + l15) * kLS;   // half B

  #pragma unroll 2
  for (int st = 0; st < 16; ++st) {
    const __bf16* __restrict__ kbh = kh  + (hbase + st) * kTile;
    const __bf16* __restrict__ kbl = klo + (hbase + st) * kTile;
    const __bf16* __restrict__ vb  = vh  + (hbase + st) * kTile;

    // ---- QK^T per s-chunk: 4 direct K-frag loads -> 12 MFMA -> exp2 -> sP ----
    #pragma unroll
    for (int sc = 0; sc < 4; ++sc) {
      bf16x8 k0 = *(const bf16x8*)&kbh[ro[sc]];
      bf16x8 k1 = *(const bf16x8*)&kbh[ro[sc] + 32];
      bf16x8 x0 = *(const bf16x8*)&kbl[ro[sc]];
      bf16x8 x1 = *(const bf16x8*)&kbl[ro[sc] + 32];
      f32x4 a0 = (f32x4){0.f, 0.f, 0.f, 0.f};
      f32x4 a1 = (f32x4){0.f, 0.f, 0.f, 0.f};
      a0 = MFMA16(k0, qlf[0][0], a0);
      a0 = MFMA16(x0, qhf[0][0], a0);
      a0 = MFMA16(k0, qhf[0][0], a0);
      a0 = MFMA16(k1, qlf[0][1], a0);
      a0 = MFMA16(x1, qhf[0][1], a0);
      a0 = MFMA16(k1, qhf[0][1], a0);
      a1 = MFMA16(k0, qlf[1][0], a1);
      a1 = MFMA16(x0, qhf[1][0], a1);
      a1 = MFMA16(k0, qhf[1][0], a1);
      a1 = MFMA16(k1, qlf[1][1], a1);
      a1 = MFMA16(x1, qhf[1][1], a1);
      a1 = MFMA16(k1, qhf[1][1], a1);
      bf16x4 p0, p1;
      #pragma unroll
      for (int r = 0; r < 4; ++r) {
        p0[r] = (__bf16)exp2f(a0[r]);
        p1[r] = (__bf16)exp2f(a1[r]);
      }
      *(bf16x4*)&sP[pw0 + sc * 16 + quad * 4] = p0;
      *(bf16x4*)&sP[pw1 + sc * 16 + quad * 4] = p1;
    }

    // ---- P frags (cross-quad relayout; in-wave DS ordering, no barrier) ----
    bf16x8 pb0[2], pb1[2];
    #pragma unroll
    for (int kc = 0; kc < 2; ++kc) {
      pb0[kc] = *(const bf16x8*)&sP[pw0 + kc * 32 + quad * 8];
      pb1[kc] = *(const bf16x8*)&sP[pw1 + kc * 32 + quad * 8];
    }
    L0 = MFMA16(ones8, pb0[0], L0);   // denominator: l[t] += sum_s P
    L0 = MFMA16(ones8, pb0[1], L0);
    L1 = MFMA16(ones8, pb1[0], L1);
    L1 = MFMA16(ones8, pb1[1], L1);

    // ---- PV: direct V-frag loads, both halves share each V frag ----
    #pragma unroll
    for (int cc = 0; cc < 4; ++cc) {
      bf16x8 v0 = *(const bf16x8*)&vb[ro[cc]];
      bf16x8 v1 = *(const bf16x8*)&vb[ro[cc] + 32];
      O0[cc] = MFMA16(v0, pb0[0], O0[cc]);
      O0[cc] = MFMA16(v1, pb0[1], O0[cc]);
      O1[cc] = MFMA16(v0, pb1[0], O1[cc]);
      O1[cc] = MFMA16(v1, pb1[1], O1[cc]);
    }
  }

  // ---- epilogue: L frag holds l[t] in every reg (col = t = l15) ----
  const float inv0 = 1.0f / L0[0];
  const float inv1 = 1.0f / L1[0];
  const int tcol = t0 + wave * 16 + l15;
  float* __restrict__ obase = out + (size_t)b * (1024 * 1024) + (size_t)(h * 64) * kT;
  #pragma unroll
  for (int cc = 0; cc < 4; ++cc) {
    #pragma unroll
    for (int r = 0; r < 4; ++r) {
      const int c = cc * 16 + quad * 4 + r;
      obase[(size_t)c * kT + tcol]      = O0[cc][r] * inv0;
      obase[(size_t)c * kT + tcol + 64] = O1[cc][r] * inv1;
    }
  }
}

// ---------------- Fallback (round-2 passing kernel, used if ws too small) ----------------
__global__ __launch_bounds__(256, 2)
void attn_fused(const float* __restrict__ qkv, const float* __restrict__ mask,
                float* __restrict__ out)
{
  __shared__ __align__(16) __bf16 Ahi[64 * kLS];
  __shared__ __align__(16) __bf16 Alo[64 * kLS];
  __shared__ __align__(16) __bf16 Vhi[64 * kLS];
  __shared__ __align__(16) __bf16 Vlo[64 * kLS];
  __shared__ __align__(16) __bf16 Phi[64 * kLS];
  __shared__ __align__(16) __bf16 Plo[64 * kLS];
  __shared__ __align__(16) float  ms[64];

  const int tid  = threadIdx.x;
  const int lane = tid & 63;
  const int wave = tid >> 6;
  const int quad = lane >> 4;
  const int l15  = lane & 15;

  const int bid = blockIdx.x;
  const int bh  = bid >> 4;
  const int tb  = bid & 15;
  const int b   = bh >> 4;
  const int h   = bh & 15;
  const int t0  = tb * 64;

  const float* __restrict__ qbase = qkv + (size_t)(b * 3072 + h * 64) * kT;
  const float* __restrict__ kbase = qkv + (size_t)(b * 3072 + 1024 + h * 64) * kT;
  const float* __restrict__ vbase = qkv + (size_t)(b * 3072 + 2048 + h * 64) * kT;
  const float* __restrict__ mrow  = mask + (size_t)(h & 7) * kT;

  const int sl = tid & 63;
  const int cg = tid >> 6;

  #pragma unroll
  for (int i = 0; i < 16; ++i) {
    const int c = cg * 16 + i;
    float v  = qbase[(size_t)c * kT + t0 + sl] * 0.125f;
    __bf16 hi = (__bf16)v;
    Ahi[sl * kLS + c] = hi;
    Alo[sl * kLS + c] = (__bf16)(v - (float)hi);
  }
  __syncthreads();

  bf16x8 qh[2], ql[2];
  {
    const int row = (wave * 16 + l15) * kLS;
    #pragma unroll
    for (int kc = 0; kc < 2; ++kc) {
      qh[kc] = *(const bf16x8*)&Ahi[row + kc * 32 + quad * 8];
      ql[kc] = *(const bf16x8*)&Alo[row + kc * 32 + quad * 8];
    }
  }
  __syncthreads();

  f32x4 O[4];
  #pragma unroll
  for (int cc = 0; cc < 4; ++cc) O[cc] = (f32x4){0.f, 0.f, 0.f, 0.f};
  float m_run = -__builtin_inff();
  float l_run = 0.f;

  for (int s0 = 0; s0 < kT; s0 += 64) {
    #pragma unroll
    for (int i = 0; i < 16; ++i) {
      const int c = cg * 16 + i;
      float kv   = kbase[(size_t)c * kT + s0 + sl];
      __bf16 khi = (__bf16)kv;
      Ahi[sl * kLS + c] = khi;
      Alo[sl * kLS + c] = (__bf16)(kv - (float)khi);
      float vv   = vbase[(size_t)c * kT + s0 + sl];
      __bf16 vhi = (__bf16)vv;
      Vhi[c * kLS + sl] = vhi;
      Vlo[c * kLS + sl] = (__bf16)(vv - (float)vhi);
    }
    if (tid < 64) ms[tid] = mrow[s0 + tid];
    __syncthreads();

    f32x4 S[4];
    #pragma unroll
    for (int sc = 0; sc < 4; ++sc) {
      f32x4 acc = (f32x4){0.f, 0.f, 0.f, 0.f};
      #pragma unroll
      for (int kc = 0; kc < 2; ++kc) {
        const int off = (sc * 16 + l15) * kLS + kc * 32 + quad * 8;
        bf16x8 kh8 = *(const bf16x8*)&Ahi[off];
        bf16x8 kl8 = *(const bf16x8*)&Alo[off];
        acc = MFMA16(kh8, ql[kc], acc);
        acc = MFMA16(kl8, qh[kc], acc);
        acc = MFMA16(kh8, qh[kc], acc);
      }
      S[sc] = acc;
    }

    float x[16];
    float tmax = -__builtin_inff();
    #pragma unroll
    for (int sc = 0; sc < 4; ++sc) {
      f32x4 mv = *(const f32x4*)&ms[sc * 16 + quad * 4];
      #pragma unroll
      for (int r = 0; r < 4; ++r) {
        float xv = S[sc][r] * mv[r];
        x[sc * 4 + r] = xv;
        tmax = fmaxf(tmax, xv);
      }
    }
    tmax = fmaxf(tmax, __shfl_xor(tmax, 16));
    tmax = fmaxf(tmax, __shfl_xor(tmax, 32));
    const float mnew  = fmaxf(m_run, tmax);
    const float alpha = __expf(m_run - mnew);
    float tsum = 0.f;
    #pragma unroll
    for (int i = 0; i < 16; ++i) {
      float p = __expf(x[i] - mnew);
      x[i] = p;
      tsum += p;
    }
    tsum += __shfl_xor(tsum, 16);
    tsum += __shfl_xor(tsum, 32);
    l_run = l_run * alpha + tsum;
    m_run = mnew;
    #pragma unroll
    for (int cc = 0; cc < 4; ++cc) O[cc] = O[cc] * alpha;

    const int prow = (wave * 16 + l15) * kLS;
    #pragma unroll
    for (int sc = 0; sc < 4; ++sc) {
      bf16x4 ph, pl;
      #pragma unroll
      for (int r = 0; r < 4; ++r) {
        float p   = x[sc * 4 + r];
        __bf16 hi = (__bf16)p;
        ph[r] = hi;
        pl[r] = (__bf16)(p - (float)hi);
      }
      *(bf16x4*)&Phi[prow + sc * 16 + quad * 4] = ph;
      *(bf16x4*)&Plo[prow + sc * 16 + quad * 4] = pl;
    }
    __syncthreads();

    bf16x8 pbh[2], pbl[2];
    #pragma unroll
    for (int kc = 0; kc < 2; ++kc) {
      pbh[kc] = *(const bf16x8*)&Phi[prow + kc * 32 + quad * 8];
      pbl[kc] = *(const bf16x8*)&Plo[prow + kc * 32 + quad * 8];
    }
    #pragma unroll
    for (int cc = 0; cc < 4; ++cc) {
      #pragma unroll
      for (int kc = 0; kc < 2; ++kc) {
        const int off = (cc * 16 + l15) * kLS + kc * 32 + quad * 8;
        bf16x8 v8 = *(const bf16x8*)&Vhi[off];
        bf16x8 w8 = *(const bf16x8*)&Vlo[off];
        O[cc] = MFMA16(v8, pbl[kc], O[cc]);
        O[cc] = MFMA16(w8, pbh[kc], O[cc]);
        O[cc] = MFMA16(v8, pbh[kc], O[cc]);
      }
    }
    __syncthreads();
  }

  const float inv  = 1.0f / l_run;
  const int   tcol = t0 + wave * 16 + l15;
  float* __restrict__ obase = out + (size_t)b * (1024 * 1024) + (size_t)(h * 64) * kT;
  #pragma unroll
  for (int cc = 0; cc < 4; ++cc) {
    #pragma unroll
    for (int r = 0; r < 4; ++r) {
      const int c = cc * 16 + quad * 4 + r;
      obase[(size_t)c * kT + tcol] = O[cc][r] * inv;
    }
  }
}

extern "C" void kernel_launch(void* const* d_in, const int* in_sizes, int n_in,
                              void* d_out, int out_size, void* d_ws, size_t ws_size,
                              hipStream_t stream)
{
  const float* qkv  = (const float*)d_in[0];  // (8, 3072, 1024) fp32
  const float* mask = (const float*)d_in[1];  // (8, 1024) fp32
  float* out = (float*)d_out;                 // (8, 1024, 1024) fp32
  (void)in_sizes; (void)n_in; (void)out_size;

  if (ws_size >= 5 * kTensorBytes) {
    char* w = (char*)d_ws;
    __bf16* qh  = (__bf16*)(w + 0 * kTensorBytes);
    __bf16* qlo = (__bf16*)(w + 1 * kTensorBytes);
    __bf16* kh  = (__bf16*)(w + 2 * kTensorBytes);
    __bf16* klo = (__bf16*)(w + 3 * kTensorBytes);
    __bf16* vh  = (__bf16*)(w + 4 * kTensorBytes);
    prepass<<<dim3(2048), dim3(256), 0, stream>>>(qkv, mask, qh, qlo, kh, klo, vh);
    attn_main<<<dim3(1024), dim3(256), 0, stream>>>(qh, qlo, kh, klo, vh, out);
  } else {
    attn_fused<<<dim3(2048), dim3(256), 0, stream>>>(qkv, mask, out);
  }
}

// Round 8
// 241.925 us; speedup vs baseline: 1.1153x; 1.1153x over previous
//
#include <hip/hip_runtime.h>
#include <stdint.h>
#include <math.h>

typedef float  f32x4  __attribute__((ext_vector_type(4)));
typedef __bf16 bf16x8 __attribute__((ext_vector_type(8)));
typedef __bf16 bf16x4 __attribute__((ext_vector_type(4)));

#define MFMA16(a, b, c) __builtin_amdgcn_mfma_f32_16x16x32_bf16((a), (b), (c), 0, 0, 0)

static constexpr int kT    = 1024;
static constexpr int kLS   = 72;            // padded row stride in bf16 (144 B, 16B-aligned)
static constexpr int kTile = 64 * kLS;      // 4608 el = 9216 B per 64x64 tile
static constexpr size_t kTensorEl    = (size_t)128 * 16 * kTile;   // 9,437,184 el
static constexpr size_t kTensorBytes = kTensorEl * 2;              // 18,874,368 B

__device__ inline void async16(const void* g, void* l) {
  __builtin_amdgcn_global_load_lds(
      (const __attribute__((address_space(1))) void*)g,
      (__attribute__((address_space(3))) void*)l, 16, 0, 0);
}

// ---------------- Prepass: fp32 -> bf16 (Q hi+lo split, K/V hi only) ----------------
// Folds: Q *= 0.125*log2(e)  (MFMA output == exp2 argument),
//        K *= mask[s]        (mask depends only on s: S*m == (m*K)^T Q).
// Layout per tensor: [bh 128][tile 16][row 64][kLS 72] bf16.
// Q^T/K^T rows = t|s, cols = c (transposed via LDS). V rows = c, cols = s (direct).
// Single 16.6 KB LDS buffer (Q then K sequentially) -> 8 blocks/CU.
__global__ __launch_bounds__(256, 8)
void prepass(const float* __restrict__ qkv, const float* __restrict__ mask,
             __bf16* __restrict__ qh, __bf16* __restrict__ qlo,
             __bf16* __restrict__ kh, __bf16* __restrict__ vh)
{
  __shared__ float ts[64 * 65];   // fp32 transpose staging (stride 65: conflict-free)
  const int tid = threadIdx.x;
  const int bid = blockIdx.x, bh = bid >> 4, tile = bid & 15;
  const int b = bh >> 4, h = bh & 15, t0 = tile * 64;
  const float* __restrict__ qb = qkv + (size_t)(b * 3072 + h * 64) * kT;
  const float* __restrict__ kb = qkv + (size_t)(b * 3072 + 1024 + h * 64) * kT;
  const float* __restrict__ vb = qkv + (size_t)(b * 3072 + 2048 + h * 64) * kT;
  const float* __restrict__ mrow = mask + (size_t)(h & 7) * kT;  // mask.repeat(n_heads,1)
  const size_t tbase = ((size_t)bh * 16 + tile) * kTile;

  const int t4   = (tid & 15) * 4;
  const int crow = tid >> 4;
  const int c0   = tid & 15;
  const int rr   = tid >> 4;

  // ---- phase 1: Q -> ts (scaled), V -> out (direct, t contiguous) ----
  #pragma unroll
  for (int i = 0; i < 4; ++i) {
    const int c = i * 16 + crow;
    f32x4 q4 = *(const f32x4*)&qb[(size_t)c * kT + t0 + t4];
    q4 *= 0.18033688f;                 // 0.125 * log2(e)
    *(f32x4*)&ts[c * 65 + t4] = q4;
    f32x4 v4 = *(const f32x4*)&vb[(size_t)c * kT + t0 + t4];
    bf16x4 v4h;
    #pragma unroll
    for (int j = 0; j < 4; ++j) v4h[j] = (__bf16)v4[j];
    *(bf16x4*)&vh[tbase + c * kLS + t4] = v4h;
  }
  __syncthreads();

  // ---- phase 2: transpose Q, split hi/lo, store ----
  #pragma unroll
  for (int i = 0; i < 4; ++i) {
    const int row = i * 16 + rr;
    bf16x4 qh4, ql4;
    #pragma unroll
    for (int j = 0; j < 4; ++j) {
      float q = ts[(c0 * 4 + j) * 65 + row];
      __bf16 qhi = (__bf16)q;
      qh4[j] = qhi; ql4[j] = (__bf16)(q - (float)qhi);
    }
    const size_t o = tbase + row * kLS + c0 * 4;
    *(bf16x4*)&qh [o] = qh4;
    *(bf16x4*)&qlo[o] = ql4;
  }
  __syncthreads();

  // ---- phase 3: K (mask-folded) -> ts ----
  const f32x4 m4 = *(const f32x4*)&mrow[t0 + t4];
  #pragma unroll
  for (int i = 0; i < 4; ++i) {
    const int c = i * 16 + crow;
    f32x4 k4 = *(const f32x4*)&kb[(size_t)c * kT + t0 + t4];
    k4 *= m4;
    *(f32x4*)&ts[c * 65 + t4] = k4;
  }
  __syncthreads();

  // ---- phase 4: transpose K, hi only ----
  #pragma unroll
  for (int i = 0; i < 4; ++i) {
    const int row = i * 16 + rr;
    bf16x4 kh4;
    #pragma unroll
    for (int j = 0; j < 4; ++j) kh4[j] = (__bf16)ts[(c0 * 4 + j) * 65 + row];
    *(bf16x4*)&kh[tbase + row * kLS + c0 * 4] = kh4;
  }
}

// ---------------- Main: flash attention, ping-pong K prefetch, 1 barrier/tile ----------------
// K tile st+1 DMA'd by wave 0 into the other LDS buffer right AFTER the barrier;
// its vmcnt drains at the NEXT barrier -> a full tile body of flight time.
// V frags load direct global->VGPR at body start, consumed at body end.
// QK is 2-term (K hi-only x Q hi/lo). Denominator via ones-MFMA C-frag.
__global__ __launch_bounds__(256, 4)
void attn_main(const __bf16* __restrict__ qh, const __bf16* __restrict__ qlo,
               const __bf16* __restrict__ kh, const __bf16* __restrict__ vh,
               float* __restrict__ out)
{
  __shared__ __align__(16) __bf16 sK[2][kTile];  // ping-pong K tiles
  __shared__ __align__(16) __bf16 sP[128 * kLS]; // rows: wave*32 + half*16 + l15

  const int tid  = threadIdx.x;
  const int lane = tid & 63;
  const int wave = tid >> 6;
  const int quad = lane >> 4;
  const int l15  = lane & 15;

  const int bid = blockIdx.x;
  const int bh  = bid & 127;       // head-major: blocks of one head share XCD
  const int tp  = bid >> 7;        // t-pair 0..7
  const int b   = bh >> 4;
  const int h   = bh & 15;
  const int t0  = tp * 128;

  const size_t hbase = (size_t)bh * 16;

  bf16x8 ones8;
  #pragma unroll
  for (int j = 0; j < 8; ++j) ones8[j] = (__bf16)1.0f;

  // per-lane fragment offsets within a 64x72 tile
  int ro[4];
  #pragma unroll
  for (int i = 0; i < 4; ++i) ro[i] = (i * 16 + l15) * kLS + quad * 8;

  // ---- Q frags: direct global loads (one-time) ----
  bf16x8 qhf[2][2], qlf[2][2];
  {
    const size_t qt0 = (hbase + tp * 2 + 0) * kTile + (size_t)(wave * 16 + l15) * kLS + quad * 8;
    const size_t qt1 = qt0 + kTile;
    #pragma unroll
    for (int kc = 0; kc < 2; ++kc) {
      qhf[0][kc] = *(const bf16x8*)&qh [qt0 + kc * 32];
      qlf[0][kc] = *(const bf16x8*)&qlo[qt0 + kc * 32];
      qhf[1][kc] = *(const bf16x8*)&qh [qt1 + kc * 32];
      qlf[1][kc] = *(const bf16x8*)&qlo[qt1 + kc * 32];
    }
  }

  // ---- prologue: DMA K tile 0 into buffer 0 ----
  if (wave == 0) {
    const char* g = (const char*)(kh + hbase * kTile) + (size_t)lane * 16;
    char* l = (char*)sK[0];
    #pragma unroll
    for (int i = 0; i < 9; ++i) async16(g + i * 1024, l + i * 1024);
  }

  f32x4 O0[4], O1[4];
  #pragma unroll
  for (int cc = 0; cc < 4; ++cc) {
    O0[cc] = (f32x4){0.f, 0.f, 0.f, 0.f};
    O1[cc] = (f32x4){0.f, 0.f, 0.f, 0.f};
  }
  f32x4 L0 = (f32x4){0.f, 0.f, 0.f, 0.f};
  f32x4 L1 = (f32x4){0.f, 0.f, 0.f, 0.f};

  const int pw0 = (wave * 32 + l15) * kLS;
  const int pw1 = pw0 + 16 * kLS;

  for (int st = 0; st < 16; ++st) {
    __syncthreads();   // K tile st complete (wave 0 drains), sK[(st-1)&1] free

    const __bf16* __restrict__ vb = vh + (hbase + st) * kTile;

    // ---- V frags half 0: issue early, consumed at body end ----
    bf16x8 vf0[4];
    #pragma unroll
    for (int cc = 0; cc < 4; ++cc) vf0[cc] = *(const bf16x8*)&vb[ro[cc]];

    // ---- prefetch K tile st+1 into the other buffer (drains at NEXT barrier) ----
    if (wave == 0 && st < 15) {
      const char* g = (const char*)(kh + (hbase + st + 1) * kTile) + (size_t)lane * 16;
      char* l = (char*)sK[(st + 1) & 1];
      #pragma unroll
      for (int i = 0; i < 9; ++i) async16(g + i * 1024, l + i * 1024);
    }

    const __bf16* __restrict__ sKc = sK[st & 1];

    // ---- QK (2-term) + exp2 -> sP, both t-halves ----
    #pragma unroll
    for (int sc = 0; sc < 4; ++sc) {
      bf16x8 k0 = *(const bf16x8*)&sKc[ro[sc]];
      bf16x8 k1 = *(const bf16x8*)&sKc[ro[sc] + 32];
      f32x4 a0 = (f32x4){0.f, 0.f, 0.f, 0.f};
      f32x4 a1 = (f32x4){0.f, 0.f, 0.f, 0.f};
      a0 = MFMA16(k0, qlf[0][0], a0);
      a0 = MFMA16(k0, qhf[0][0], a0);
      a0 = MFMA16(k1, qlf[0][1], a0);
      a0 = MFMA16(k1, qhf[0][1], a0);
      a1 = MFMA16(k0, qlf[1][0], a1);
      a1 = MFMA16(k0, qhf[1][0], a1);
      a1 = MFMA16(k1, qlf[1][1], a1);
      a1 = MFMA16(k1, qhf[1][1], a1);
      bf16x4 p0, p1;
      #pragma unroll
      for (int r = 0; r < 4; ++r) {
        p0[r] = (__bf16)exp2f(a0[r]);
        p1[r] = (__bf16)exp2f(a1[r]);
      }
      *(bf16x4*)&sP[pw0 + sc * 16 + quad * 4] = p0;
      *(bf16x4*)&sP[pw1 + sc * 16 + quad * 4] = p1;
    }

    // ---- V frags half 1 ----
    bf16x8 vf1[4];
    #pragma unroll
    for (int cc = 0; cc < 4; ++cc) vf1[cc] = *(const bf16x8*)&vb[ro[cc] + 32];

    // ---- P frags (cross-quad relayout; in-wave DS ordering) + denominator ----
    bf16x8 pb0[2], pb1[2];
    #pragma unroll
    for (int kc = 0; kc < 2; ++kc) {
      pb0[kc] = *(const bf16x8*)&sP[pw0 + kc * 32 + quad * 8];
      pb1[kc] = *(const bf16x8*)&sP[pw1 + kc * 32 + quad * 8];
    }
    L0 = MFMA16(ones8, pb0[0], L0);
    L0 = MFMA16(ones8, pb0[1], L0);
    L1 = MFMA16(ones8, pb1[0], L1);
    L1 = MFMA16(ones8, pb1[1], L1);

    // ---- PV: V frags shared by both halves ----
    #pragma unroll
    for (int cc = 0; cc < 4; ++cc) {
      O0[cc] = MFMA16(vf0[cc], pb0[0], O0[cc]);
      O0[cc] = MFMA16(vf1[cc], pb0[1], O0[cc]);
      O1[cc] = MFMA16(vf0[cc], pb1[0], O1[cc]);
      O1[cc] = MFMA16(vf1[cc], pb1[1], O1[cc]);
    }
  }

  // ---- epilogue: L frag holds l[t] in every reg (col = t = l15) ----
  const float inv0 = 1.0f / L0[0];
  const float inv1 = 1.0f / L1[0];
  const int tcol = t0 + wave * 16 + l15;
  float* __restrict__ obase = out + (size_t)b * (1024 * 1024) + (size_t)(h * 64) * kT;
  #pragma unroll
  for (int cc = 0; cc < 4; ++cc) {
    #pragma unroll
    for (int r = 0; r < 4; ++r) {
      const int c = cc * 16 + quad * 4 + r;
      obase[(size_t)c * kT + tcol]      = O0[cc][r] * inv0;
      obase[(size_t)c * kT + tcol + 64] = O1[cc][r] * inv1;
    }
  }
}

// ---------------- Fallback (round-2 passing kernel, used if ws too small) ----------------
__global__ __launch_bounds__(256, 2)
void attn_fused(const float* __restrict__ qkv, const float* __restrict__ mask,
                float* __restrict__ out)
{
  __shared__ __align__(16) __bf16 Ahi[64 * kLS];
  __shared__ __align__(16) __bf16 Alo[64 * kLS];
  __shared__ __align__(16) __bf16 Vhi[64 * kLS];
  __shared__ __align__(16) __bf16 Vlo[64 * kLS];
  __shared__ __align__(16) __bf16 Phi[64 * kLS];
  __shared__ __align__(16) __bf16 Plo[64 * kLS];
  __shared__ __align__(16) float  ms[64];

  const int tid  = threadIdx.x;
  const int lane = tid & 63;
  const int wave = tid >> 6;
  const int quad = lane >> 4;
  const int l15  = lane & 15;

  const int bid = blockIdx.x;
  const int bh  = bid >> 4;
  const int tb  = bid & 15;
  const int b   = bh >> 4;
  const int h   = bh & 15;
  const int t0  = tb * 64;

  const float* __restrict__ qbase = qkv + (size_t)(b * 3072 + h * 64) * kT;
  const float* __restrict__ kbase = qkv + (size_t)(b * 3072 + 1024 + h * 64) * kT;
  const float* __restrict__ vbase = qkv + (size_t)(b * 3072 + 2048 + h * 64) * kT;
  const float* __restrict__ mrow  = mask + (size_t)(h & 7) * kT;

  const int sl = tid & 63;
  const int cg = tid >> 6;

  #pragma unroll
  for (int i = 0; i < 16; ++i) {
    const int c = cg * 16 + i;
    float v  = qbase[(size_t)c * kT + t0 + sl] * 0.125f;
    __bf16 hi = (__bf16)v;
    Ahi[sl * kLS + c] = hi;
    Alo[sl * kLS + c] = (__bf16)(v - (float)hi);
  }
  __syncthreads();

  bf16x8 qh[2], ql[2];
  {
    const int row = (wave * 16 + l15) * kLS;
    #pragma unroll
    for (int kc = 0; kc < 2; ++kc) {
      qh[kc] = *(const bf16x8*)&Ahi[row + kc * 32 + quad * 8];
      ql[kc] = *(const bf16x8*)&Alo[row + kc * 32 + quad * 8];
    }
  }
  __syncthreads();

  f32x4 O[4];
  #pragma unroll
  for (int cc = 0; cc < 4; ++cc) O[cc] = (f32x4){0.f, 0.f, 0.f, 0.f};
  float m_run = -__builtin_inff();
  float l_run = 0.f;

  for (int s0 = 0; s0 < kT; s0 += 64) {
    #pragma unroll
    for (int i = 0; i < 16; ++i) {
      const int c = cg * 16 + i;
      float kv   = kbase[(size_t)c * kT + s0 + sl];
      __bf16 khi = (__bf16)kv;
      Ahi[sl * kLS + c] = khi;
      Alo[sl * kLS + c] = (__bf16)(kv - (float)khi);
      float vv   = vbase[(size_t)c * kT + s0 + sl];
      __bf16 vhi = (__bf16)vv;
      Vhi[c * kLS + sl] = vhi;
      Vlo[c * kLS + sl] = (__bf16)(vv - (float)vhi);
    }
    if (tid < 64) ms[tid] = mrow[s0 + tid];
    __syncthreads();

    f32x4 S[4];
    #pragma unroll
    for (int sc = 0; sc < 4; ++sc) {
      f32x4 acc = (f32x4){0.f, 0.f, 0.f, 0.f};
      #pragma unroll
      for (int kc = 0; kc < 2; ++kc) {
        const int off = (sc * 16 + l15) * kLS + kc * 32 + quad * 8;
        bf16x8 kh8 = *(const bf16x8*)&Ahi[off];
        bf16x8 kl8 = *(const bf16x8*)&Alo[off];
        acc = MFMA16(kh8, ql[kc], acc);
        acc = MFMA16(kl8, qh[kc], acc);
        acc = MFMA16(kh8, qh[kc], acc);
      }
      S[sc] = acc;
    }

    float x[16];
    float tmax = -__builtin_inff();
    #pragma unroll
    for (int sc = 0; sc < 4; ++sc) {
      f32x4 mv = *(const f32x4*)&ms[sc * 16 + quad * 4];
      #pragma unroll
      for (int r = 0; r < 4; ++r) {
        float xv = S[sc][r] * mv[r];
        x[sc * 4 + r] = xv;
        tmax = fmaxf(tmax, xv);
      }
    }
    tmax = fmaxf(tmax, __shfl_xor(tmax, 16));
    tmax = fmaxf(tmax, __shfl_xor(tmax, 32));
    const float mnew  = fmaxf(m_run, tmax);
    const float alpha = __expf(m_run - mnew);
    float tsum = 0.f;
    #pragma unroll
    for (int i = 0; i < 16; ++i) {
      float p = __expf(x[i] - mnew);
      x[i] = p;
      tsum += p;
    }
    tsum += __shfl_xor(tsum, 16);
    tsum += __shfl_xor(tsum, 32);
    l_run = l_run * alpha + tsum;
    m_run = mnew;
    #pragma unroll
    for (int cc = 0; cc < 4; ++cc) O[cc] = O[cc] * alpha;

    const int prow = (wave * 16 + l15) * kLS;
    #pragma unroll
    for (int sc = 0; sc < 4; ++sc) {
      bf16x4 ph, pl;
      #pragma unroll
      for (int r = 0; r < 4; ++r) {
        float p   = x[sc * 4 + r];
        __bf16 hi = (__bf16)p;
        ph[r] = hi;
        pl[r] = (__bf16)(p - (float)hi);
      }
      *(bf16x4*)&Phi[prow + sc * 16 + quad * 4] = ph;
      *(bf16x4*)&Plo[prow + sc * 16 + quad * 4] = pl;
    }
    __syncthreads();

    bf16x8 pbh[2], pbl[2];
    #pragma unroll
    for (int kc = 0; kc < 2; ++kc) {
      pbh[kc] = *(const bf16x8*)&Phi[prow + kc * 32 + quad * 8];
      pbl[kc] = *(const bf16x8*)&Plo[prow + kc * 32 + quad * 8];
    }
    #pragma unroll
    for (int cc = 0; cc < 4; ++cc) {
      #pragma unroll
      for (int kc = 0; kc < 2; ++kc) {
        const int off = (cc * 16 + l15) * kLS + kc * 32 + quad * 8;
        bf16x8 v8 = *(const bf16x8*)&Vhi[off];
        bf16x8 w8 = *(const bf16x8*)&Vlo[off];
        O[cc] = MFMA16(v8, pbl[kc], O[cc]);
        O[cc] = MFMA16(w8, pbh[kc], O[cc]);
        O[cc] = MFMA16(v8, pbh[kc], O[cc]);
      }
    }
    __syncthreads();
  }

  const float inv  = 1.0f / l_run;
  const int   tcol = t0 + wave * 16 + l15;
  float* __restrict__ obase = out + (size_t)b * (1024 * 1024) + (size_t)(h * 64) * kT;
  #pragma unroll
  for (int cc = 0; cc < 4; ++cc) {
    #pragma unroll
    for (int r = 0; r < 4; ++r) {
      const int c = cc * 16 + quad * 4 + r;
      obase[(size_t)c * kT + tcol] = O[cc][r] * inv;
    }
  }
}

extern "C" void kernel_launch(void* const* d_in, const int* in_sizes, int n_in,
                              void* d_out, int out_size, void* d_ws, size_t ws_size,
                              hipStream_t stream)
{
  const float* qkv  = (const float*)d_in[0];  // (8, 3072, 1024) fp32
  const float* mask = (const float*)d_in[1];  // (8, 1024) fp32
  float* out = (float*)d_out;                 // (8, 1024, 1024) fp32
  (void)in_sizes; (void)n_in; (void)out_size;

  if (ws_size >= 4 * kTensorBytes) {
    char* w = (char*)d_ws;
    __bf16* qh  = (__bf16*)(w + 0 * kTensorBytes);
    __bf16* qlo = (__bf16*)(w + 1 * kTensorBytes);
    __bf16* kh  = (__bf16*)(w + 2 * kTensorBytes);
    __bf16* vh  = (__bf16*)(w + 3 * kTensorBytes);
    prepass<<<dim3(2048), dim3(256), 0, stream>>>(qkv, mask, qh, qlo, kh, vh);
    attn_main<<<dim3(1024), dim3(256), 0, stream>>>(qh, qlo, kh, vh, out);
  } else {
    attn_fused<<<dim3(2048), dim3(256), 0, stream>>>(qkv, mask, out);
  }
}

// Round 9
// 210.173 us; speedup vs baseline: 1.2838x; 1.1511x over previous
//
#include <hip/hip_runtime.h>
#include <stdint.h>
#include <math.h>

typedef float  f32x4  __attribute__((ext_vector_type(4)));
typedef __bf16 bf16x8 __attribute__((ext_vector_type(8)));
typedef __bf16 bf16x4 __attribute__((ext_vector_type(4)));

#define MFMA16(a, b, c) __builtin_amdgcn_mfma_f32_16x16x32_bf16((a), (b), (c), 0, 0, 0)
#define EXP2(x) __builtin_amdgcn_exp2f(x)   // native v_exp_f32, no libm expansion

static constexpr int kT    = 1024;
static constexpr int kLS   = 72;            // padded row stride in bf16 (144 B, 16B-aligned)
static constexpr int kTile = 64 * kLS;      // 4608 el = 9216 B per 64x64 tile
static constexpr size_t kTensorEl    = (size_t)128 * 16 * kTile;   // 9,437,184 el
static constexpr size_t kTensorBytes = kTensorEl * 2;              // 18,874,368 B

__device__ inline void async16(const void* g, void* l) {
  __builtin_amdgcn_global_load_lds(
      (const __attribute__((address_space(1))) void*)g,
      (__attribute__((address_space(3))) void*)l, 16, 0, 0);
}

// ---------------- Prepass: K (mask-folded, transposed, bf16 hi) + V (bf16 hi) only ----------------
// K *= mask[s] folds the mask (s-only dependence) into the QK product.
// Layout per tensor: [bh 128][tile 16][row 64][kLS 72] bf16.
// K^T rows = s, cols = c (transposed via LDS, stride-65 conflict-free). V rows = c, cols = s.
// Q is NOT processed here — attn_main transposes it in its prologue (used once per block).
__global__ __launch_bounds__(256, 8)
void prepass(const float* __restrict__ qkv, const float* __restrict__ mask,
             __bf16* __restrict__ kh, __bf16* __restrict__ vh)
{
  __shared__ float ts[64 * 65];
  const int tid = threadIdx.x;
  const int bid = blockIdx.x, bh = bid >> 4, tile = bid & 15;
  const int b = bh >> 4, h = bh & 15, t0 = tile * 64;
  const float* __restrict__ kb = qkv + (size_t)(b * 3072 + 1024 + h * 64) * kT;
  const float* __restrict__ vb = qkv + (size_t)(b * 3072 + 2048 + h * 64) * kT;
  const float* __restrict__ mrow = mask + (size_t)(h & 7) * kT;  // mask.repeat(n_heads,1)
  const size_t tbase = ((size_t)bh * 16 + tile) * kTile;

  const int t4   = (tid & 15) * 4;
  const int crow = tid >> 4;
  const f32x4 m4 = *(const f32x4*)&mrow[t0 + t4];

  #pragma unroll
  for (int i = 0; i < 4; ++i) {
    const int c = i * 16 + crow;
    f32x4 k4 = *(const f32x4*)&kb[(size_t)c * kT + t0 + t4];
    k4 *= m4;                               // fold mask into K rows (s-axis)
    *(f32x4*)&ts[c * 65 + t4] = k4;
    f32x4 v4 = *(const f32x4*)&vb[(size_t)c * kT + t0 + t4];
    bf16x4 v4h;
    #pragma unroll
    for (int j = 0; j < 4; ++j) v4h[j] = (__bf16)v4[j];
    *(bf16x4*)&vh[tbase + c * kLS + t4] = v4h;
  }
  __syncthreads();

  const int c0 = tid & 15;
  const int rr = tid >> 4;
  #pragma unroll
  for (int i = 0; i < 4; ++i) {
    const int row = i * 16 + rr;
    bf16x4 kh4;
    #pragma unroll
    for (int j = 0; j < 4; ++j) kh4[j] = (__bf16)ts[(c0 * 4 + j) * 65 + row];
    *(bf16x4*)&kh[tbase + row * kLS + c0 * 4] = kh4;
  }
}

// ---------------- Main: flash attention, ping-pong K prefetch, 1 barrier/tile ----------------
// Prologue: Q loaded fp32 from qkv, scaled by 0.125*log2(e), transposed via LDS
// (frag reads are 2-way bank-aliased = free), split hi/lo into registers.
// Loop: K tile st+1 DMA'd (distributed across all 4 waves) into the other LDS buffer
// right after the barrier; drains at the NEXT barrier -> full tile body of flight time.
// V frags load direct global->VGPR. QK 2-term (K hi x Q hi/lo). Denominator via ones-MFMA.
__global__ __launch_bounds__(256, 4)
void attn_main(const float* __restrict__ qkv,
               const __bf16* __restrict__ kh, const __bf16* __restrict__ vh,
               float* __restrict__ out)
{
  __shared__ __align__(16) __bf16 sK[2][kTile];  // ping-pong K tiles; also fp32 Q staging
  __shared__ __align__(16) __bf16 sP[128 * kLS]; // rows: wave*32 + half*16 + l15

  const int tid  = threadIdx.x;
  const int lane = tid & 63;
  const int wave = tid >> 6;
  const int quad = lane >> 4;
  const int l15  = lane & 15;

  const int bid = blockIdx.x;
  const int bh  = bid & 127;       // head-major: blocks of one head share XCD
  const int tp  = bid >> 7;        // t-pair 0..7
  const int b   = bh >> 4;
  const int h   = bh & 15;
  const int t0  = tp * 128;

  const size_t hbase = (size_t)bh * 16;

  bf16x8 ones8;
  #pragma unroll
  for (int j = 0; j < 8; ++j) ones8[j] = (__bf16)1.0f;

  // per-lane fragment offsets within a 64x72 tile
  int ro[4];
  #pragma unroll
  for (int i = 0; i < 4; ++i) ro[i] = (i * 16 + l15) * kLS + quad * 8;

  // ---- prologue: Q fp32 -> LDS transpose -> hi/lo register frags (both t-halves) ----
  bf16x8 qhf[2][2], qlf[2][2];
  {
    float* ts = (float*)sK;   // 64*65*4 = 16.64 KB fits in sK's 18.4 KB
    const float* __restrict__ qb = qkv + (size_t)(b * 3072 + h * 64) * kT;
    const int t4   = (tid & 15) * 4;
    const int crow = tid >> 4;
    const int trow = wave * 16 + l15;
    #pragma unroll
    for (int half = 0; half < 2; ++half) {
      const int tq0 = t0 + half * 64;
      #pragma unroll
      for (int i = 0; i < 4; ++i) {
        const int c = i * 16 + crow;
        f32x4 q4 = *(const f32x4*)&qb[(size_t)c * kT + tq0 + t4];
        q4 *= 0.18033688f;                 // 0.125 * log2(e)
        *(f32x4*)&ts[c * 65 + t4] = q4;
      }
      __syncthreads();
      #pragma unroll
      for (int kc = 0; kc < 2; ++kc) {
        bf16x8 hf, lf;
        #pragma unroll
        for (int j = 0; j < 8; ++j) {
          float q = ts[(kc * 32 + quad * 8 + j) * 65 + trow];  // 2-way bank alias: free
          __bf16 hi = (__bf16)q;
          hf[j] = hi;
          lf[j] = (__bf16)(q - (float)hi);
        }
        qhf[half][kc] = hf;
        qlf[half][kc] = lf;
      }
      __syncthreads();   // also protects sK reuse below
    }
  }

  // ---- DMA K tile 0 into buffer 0, distributed across waves ----
  {
    const char* g = (const char*)(kh + hbase * kTile) + (size_t)lane * 16;
    char* l = (char*)sK[0];
    for (int i = wave; i < 9; i += 4) async16(g + i * 1024, l + i * 1024);
  }

  f32x4 O0[4], O1[4];
  #pragma unroll
  for (int cc = 0; cc < 4; ++cc) {
    O0[cc] = (f32x4){0.f, 0.f, 0.f, 0.f};
    O1[cc] = (f32x4){0.f, 0.f, 0.f, 0.f};
  }
  f32x4 L0 = (f32x4){0.f, 0.f, 0.f, 0.f};
  f32x4 L1 = (f32x4){0.f, 0.f, 0.f, 0.f};

  const int pw0 = (wave * 32 + l15) * kLS;
  const int pw1 = pw0 + 16 * kLS;

  for (int st = 0; st < 16; ++st) {
    __syncthreads();   // K tile st drained (all waves), sK[(st-1)&1] free

    const __bf16* __restrict__ vb = vh + (hbase + st) * kTile;

    // ---- V frags half 0: issue early, consumed at body end ----
    bf16x8 vf0[4];
    #pragma unroll
    for (int cc = 0; cc < 4; ++cc) vf0[cc] = *(const bf16x8*)&vb[ro[cc]];

    // ---- prefetch K tile st+1 (distributed); drains at NEXT barrier ----
    if (st < 15) {
      const char* g = (const char*)(kh + (hbase + st + 1) * kTile) + (size_t)lane * 16;
      char* l = (char*)sK[(st + 1) & 1];
      for (int i = wave; i < 9; i += 4) async16(g + i * 1024, l + i * 1024);
    }

    const __bf16* __restrict__ sKc = sK[st & 1];

    // ---- QK (2-term) + exp2 -> sP, both t-halves ----
    #pragma unroll
    for (int sc = 0; sc < 4; ++sc) {
      bf16x8 k0 = *(const bf16x8*)&sKc[ro[sc]];
      bf16x8 k1 = *(const bf16x8*)&sKc[ro[sc] + 32];
      f32x4 a0 = (f32x4){0.f, 0.f, 0.f, 0.f};
      f32x4 a1 = (f32x4){0.f, 0.f, 0.f, 0.f};
      a0 = MFMA16(k0, qlf[0][0], a0);
      a0 = MFMA16(k0, qhf[0][0], a0);
      a0 = MFMA16(k1, qlf[0][1], a0);
      a0 = MFMA16(k1, qhf[0][1], a0);
      a1 = MFMA16(k0, qlf[1][0], a1);
      a1 = MFMA16(k0, qhf[1][0], a1);
      a1 = MFMA16(k1, qlf[1][1], a1);
      a1 = MFMA16(k1, qhf[1][1], a1);
      bf16x4 p0, p1;
      #pragma unroll
      for (int r = 0; r < 4; ++r) {
        p0[r] = (__bf16)EXP2(a0[r]);
        p1[r] = (__bf16)EXP2(a1[r]);
      }
      *(bf16x4*)&sP[pw0 + sc * 16 + quad * 4] = p0;
      *(bf16x4*)&sP[pw1 + sc * 16 + quad * 4] = p1;
    }

    // ---- V frags half 1 ----
    bf16x8 vf1[4];
    #pragma unroll
    for (int cc = 0; cc < 4; ++cc) vf1[cc] = *(const bf16x8*)&vb[ro[cc] + 32];

    // ---- P frags (cross-quad relayout; in-wave DS ordering) + denominator ----
    bf16x8 pb0[2], pb1[2];
    #pragma unroll
    for (int kc = 0; kc < 2; ++kc) {
      pb0[kc] = *(const bf16x8*)&sP[pw0 + kc * 32 + quad * 8];
      pb1[kc] = *(const bf16x8*)&sP[pw1 + kc * 32 + quad * 8];
    }
    L0 = MFMA16(ones8, pb0[0], L0);
    L0 = MFMA16(ones8, pb0[1], L0);
    L1 = MFMA16(ones8, pb1[0], L1);
    L1 = MFMA16(ones8, pb1[1], L1);

    // ---- PV: V frags shared by both halves ----
    #pragma unroll
    for (int cc = 0; cc < 4; ++cc) {
      O0[cc] = MFMA16(vf0[cc], pb0[0], O0[cc]);
      O0[cc] = MFMA16(vf1[cc], pb0[1], O0[cc]);
      O1[cc] = MFMA16(vf0[cc], pb1[0], O1[cc]);
      O1[cc] = MFMA16(vf1[cc], pb1[1], O1[cc]);
    }
  }

  // ---- epilogue: L frag holds l[t] in every reg (col = t = l15) ----
  const float inv0 = 1.0f / L0[0];
  const float inv1 = 1.0f / L1[0];
  const int tcol = t0 + wave * 16 + l15;
  float* __restrict__ obase = out + (size_t)b * (1024 * 1024) + (size_t)(h * 64) * kT;
  #pragma unroll
  for (int cc = 0; cc < 4; ++cc) {
    #pragma unroll
    for (int r = 0; r < 4; ++r) {
      const int c = cc * 16 + quad * 4 + r;
      obase[(size_t)c * kT + tcol]      = O0[cc][r] * inv0;
      obase[(size_t)c * kT + tcol + 64] = O1[cc][r] * inv1;
    }
  }
}

// ---------------- Fallback (round-2 passing kernel, used if ws too small) ----------------
__global__ __launch_bounds__(256, 2)
void attn_fused(const float* __restrict__ qkv, const float* __restrict__ mask,
                float* __restrict__ out)
{
  __shared__ __align__(16) __bf16 Ahi[64 * kLS];
  __shared__ __align__(16) __bf16 Alo[64 * kLS];
  __shared__ __align__(16) __bf16 Vhi[64 * kLS];
  __shared__ __align__(16) __bf16 Vlo[64 * kLS];
  __shared__ __align__(16) __bf16 Phi[64 * kLS];
  __shared__ __align__(16) __bf16 Plo[64 * kLS];
  __shared__ __align__(16) float  ms[64];

  const int tid  = threadIdx.x;
  const int lane = tid & 63;
  const int wave = tid >> 6;
  const int quad = lane >> 4;
  const int l15  = lane & 15;

  const int bid = blockIdx.x;
  const int bh  = bid >> 4;
  const int tb  = bid & 15;
  const int b   = bh >> 4;
  const int h   = bh & 15;
  const int t0  = tb * 64;

  const float* __restrict__ qbase = qkv + (size_t)(b * 3072 + h * 64) * kT;
  const float* __restrict__ kbase = qkv + (size_t)(b * 3072 + 1024 + h * 64) * kT;
  const float* __restrict__ vbase = qkv + (size_t)(b * 3072 + 2048 + h * 64) * kT;
  const float* __restrict__ mrow  = mask + (size_t)(h & 7) * kT;

  const int sl = tid & 63;
  const int cg = tid >> 6;

  #pragma unroll
  for (int i = 0; i < 16; ++i) {
    const int c = cg * 16 + i;
    float v  = qbase[(size_t)c * kT + t0 + sl] * 0.125f;
    __bf16 hi = (__bf16)v;
    Ahi[sl * kLS + c] = hi;
    Alo[sl * kLS + c] = (__bf16)(v - (float)hi);
  }
  __syncthreads();

  bf16x8 qh[2], ql[2];
  {
    const int row = (wave * 16 + l15) * kLS;
    #pragma unroll
    for (int kc = 0; kc < 2; ++kc) {
      qh[kc] = *(const bf16x8*)&Ahi[row + kc * 32 + quad * 8];
      ql[kc] = *(const bf16x8*)&Alo[row + kc * 32 + quad * 8];
    }
  }
  __syncthreads();

  f32x4 O[4];
  #pragma unroll
  for (int cc = 0; cc < 4; ++cc) O[cc] = (f32x4){0.f, 0.f, 0.f, 0.f};
  float m_run = -__builtin_inff();
  float l_run = 0.f;

  for (int s0 = 0; s0 < kT; s0 += 64) {
    #pragma unroll
    for (int i = 0; i < 16; ++i) {
      const int c = cg * 16 + i;
      float kv   = kbase[(size_t)c * kT + s0 + sl];
      __bf16 khi = (__bf16)kv;
      Ahi[sl * kLS + c] = khi;
      Alo[sl * kLS + c] = (__bf16)(kv - (float)khi);
      float vv   = vbase[(size_t)c * kT + s0 + sl];
      __bf16 vhi = (__bf16)vv;
      Vhi[c * kLS + sl] = vhi;
      Vlo[c * kLS + sl] = (__bf16)(vv - (float)vhi);
    }
    if (tid < 64) ms[tid] = mrow[s0 + tid];
    __syncthreads();

    f32x4 S[4];
    #pragma unroll
    for (int sc = 0; sc < 4; ++sc) {
      f32x4 acc = (f32x4){0.f, 0.f, 0.f, 0.f};
      #pragma unroll
      for (int kc = 0; kc < 2; ++kc) {
        const int off = (sc * 16 + l15) * kLS + kc * 32 + quad * 8;
        bf16x8 kh8 = *(const bf16x8*)&Ahi[off];
        bf16x8 kl8 = *(const bf16x8*)&Alo[off];
        acc = MFMA16(kh8, ql[kc], acc);
        acc = MFMA16(kl8, qh[kc], acc);
        acc = MFMA16(kh8, qh[kc], acc);
      }
      S[sc] = acc;
    }

    float x[16];
    float tmax = -__builtin_inff();
    #pragma unroll
    for (int sc = 0; sc < 4; ++sc) {
      f32x4 mv = *(const f32x4*)&ms[sc * 16 + quad * 4];
      #pragma unroll
      for (int r = 0; r < 4; ++r) {
        float xv = S[sc][r] * mv[r];
        x[sc * 4 + r] = xv;
        tmax = fmaxf(tmax, xv);
      }
    }
    tmax = fmaxf(tmax, __shfl_xor(tmax, 16));
    tmax = fmaxf(tmax, __shfl_xor(tmax, 32));
    const float mnew  = fmaxf(m_run, tmax);
    const float alpha = __expf(m_run - mnew);
    float tsum = 0.f;
    #pragma unroll
    for (int i = 0; i < 16; ++i) {
      float p = __expf(x[i] - mnew);
      x[i] = p;
      tsum += p;
    }
    tsum += __shfl_xor(tsum, 16);
    tsum += __shfl_xor(tsum, 32);
    l_run = l_run * alpha + tsum;
    m_run = mnew;
    #pragma unroll
    for (int cc = 0; cc < 4; ++cc) O[cc] = O[cc] * alpha;

    const int prow = (wave * 16 + l15) * kLS;
    #pragma unroll
    for (int sc = 0; sc < 4; ++sc) {
      bf16x4 ph, pl;
      #pragma unroll
      for (int r = 0; r < 4; ++r) {
        float p   = x[sc * 4 + r];
        __bf16 hi = (__bf16)p;
        ph[r] = hi;
        pl[r] = (__bf16)(p - (float)hi);
      }
      *(bf16x4*)&Phi[prow + sc * 16 + quad * 4] = ph;
      *(bf16x4*)&Plo[prow + sc * 16 + quad * 4] = pl;
    }
    __syncthreads();

    bf16x8 pbh[2], pbl[2];
    #pragma unroll
    for (int kc = 0; kc < 2; ++kc) {
      pbh[kc] = *(const bf16x8*)&Phi[prow + kc * 32 + quad * 8];
      pbl[kc] = *(const bf16x8*)&Plo[prow + kc * 32 + quad * 8];
    }
    #pragma unroll
    for (int cc = 0; cc < 4; ++cc) {
      #pragma unroll
      for (int kc = 0; kc < 2; ++kc) {
        const int off = (cc * 16 + l15) * kLS + kc * 32 + quad * 8;
        bf16x8 v8 = *(const bf16x8*)&Vhi[off];
        bf16x8 w8 = *(const bf16x8*)&Vlo[off];
        O[cc] = MFMA16(v8, pbl[kc], O[cc]);
        O[cc] = MFMA16(w8, pbh[kc], O[cc]);
        O[cc] = MFMA16(v8, pbh[kc], O[cc]);
      }
    }
    __syncthreads();
  }

  const float inv  = 1.0f / l_run;
  const int   tcol = t0 + wave * 16 + l15;
  float* __restrict__ obase = out + (size_t)b * (1024 * 1024) + (size_t)(h * 64) * kT;
  #pragma unroll
  for (int cc = 0; cc < 4; ++cc) {
    #pragma unroll
    for (int r = 0; r < 4; ++r) {
      const int c = cc * 16 + quad * 4 + r;
      obase[(size_t)c * kT + tcol] = O[cc][r] * inv;
    }
  }
}

extern "C" void kernel_launch(void* const* d_in, const int* in_sizes, int n_in,
                              void* d_out, int out_size, void* d_ws, size_t ws_size,
                              hipStream_t stream)
{
  const float* qkv  = (const float*)d_in[0];  // (8, 3072, 1024) fp32
  const float* mask = (const float*)d_in[1];  // (8, 1024) fp32
  float* out = (float*)d_out;                 // (8, 1024, 1024) fp32
  (void)in_sizes; (void)n_in; (void)out_size;

  if (ws_size >= 2 * kTensorBytes) {
    char* w = (char*)d_ws;
    __bf16* kh = (__bf16*)(w + 0 * kTensorBytes);
    __bf16* vh = (__bf16*)(w + 1 * kTensorBytes);
    prepass<<<dim3(2048), dim3(256), 0, stream>>>(qkv, mask, kh, vh);
    attn_main<<<dim3(1024), dim3(256), 0, stream>>>(qkv, kh, vh, out);
  } else {
    attn_fused<<<dim3(2048), dim3(256), 0, stream>>>(qkv, mask, out);
  }
}